// Round 2
// baseline (404.423 us; speedup 1.0000x reference)
//
#include <hip/hip_runtime.h>
#include <stdint.h>

// Tree-LSTM scan: B=256, L=128, STATE=128, INIT=256, Z=5*128=640. fp32 I/O.
// 16 blocks x 512 threads; block owns 16 batch rows; bf16 weights register-
// resident (160 VGPR/thread); recurrence block-local (no grid sync).

constexpr int kL      = 128;
constexpr int kState  = 128;
constexpr int kInit   = 256;
constexpr int kRows   = 16;
constexpr int kBlocks = 16;
constexpr int kThreads= 512;
constexpr int kHxStr  = 264;   // bf16 elems: [h 0:128 | x_rh 128:256 | pad 8]
constexpr int kXcStr  = 132;   // fp32 elems: right_c 128 + pad 4

typedef __attribute__((ext_vector_type(8))) short short8;    // MFMA A/B frag
typedef __attribute__((ext_vector_type(4))) short short4v;
typedef __attribute__((ext_vector_type(4))) float floatx4;   // MFMA C/D frag

__device__ __forceinline__ uint16_t f2bf(float f) {
    union { float f; uint32_t i; } v; v.f = f;
    return (uint16_t)((v.i + 0x7FFFu + ((v.i >> 16) & 1u)) >> 16);  // RNE
}
__device__ __forceinline__ short8 cvt8(const float* p) {
    float4 a = ((const float4*)p)[0];
    float4 b = ((const float4*)p)[1];
    short8 r;
    r[0]=f2bf(a.x); r[1]=f2bf(a.y); r[2]=f2bf(a.z); r[3]=f2bf(a.w);
    r[4]=f2bf(b.x); r[5]=f2bf(b.y); r[6]=f2bf(b.z); r[7]=f2bf(b.w);
    return r;
}
__device__ __forceinline__ float clampf(float x, float lo, float hi) {
    return fminf(fmaxf(x, lo), hi);
}

__global__ __launch_bounds__(kThreads, 2)
void tree_lstm_kernel(const int* __restrict__ ids,
                      const float* __restrict__ embed,
                      const float* __restrict__ whx_w,
                      const float* __restrict__ whx_b,
                      const float* __restrict__ init_state,
                      const float* __restrict__ final_w,
                      const float* __restrict__ final_b,
                      float* __restrict__ out)
{
    __shared__ alignas(16) uint16_t hx[2][kRows][kHxStr];  // bf16 [h | right_h]
    __shared__ alignas(16) float    xcf[2][kRows][kXcStr]; // fp32 right_c
    __shared__ int   ids_l[kRows * kL];
    __shared__ float hfin[kRows][kState + 4];              // fp32 final h
    __shared__ float partial[kRows][3][4];

    const int tid  = threadIdx.x;
    const int w    = tid >> 6;        // wave 0..7 -> j-slice [16w,16w+16)
    const int lane = tid & 63;
    const int l15  = lane & 15;       // batch row (MFMA D col / B col)
    const int quad = lane >> 4;       // 0..3
    const int b0   = blockIdx.x * kRows;
    const int j0   = w * 16 + quad * 4;   // 4 consecutive j (MFMA D rows)
    const int row  = tid >> 5;        // staging: batch row 0..15
    const int c16  = tid & 31;        // staging: 8-elem chunk of 256-elem x row

    // ids -> LDS, coalesced
    ((int4*)ids_l)[tid] = ((const int4*)(ids + b0 * kL))[tid];

    // register-resident A-frags of z^T = W * hx^T (fp32 -> bf16 RNE)
    // A layout: m = lane&15 (W row n0+l15), k = kk*32 + quad*8 + [0..8)
    short8 wf[5][8];
#pragma unroll
    for (int g = 0; g < 5; ++g) {
        const float* wrow = whx_w + (size_t)(g * 128 + w * 16 + l15) * kInit;
#pragma unroll
        for (int kk = 0; kk < 8; ++kk)
            wf[g][kk] = cvt8(wrow + kk * 32 + quad * 8);
    }

    // bias aligned to D rows: bias4[g][r] = whx_b[128g + j0 + r]
    floatx4 bias4[5];
#pragma unroll
    for (int g = 0; g < 5; ++g) {
#pragma unroll
        for (int r = 0; r < 4; ++r) bias4[g][r] = whx_b[g * 128 + j0 + r];
    }

    // init h0 (bf16 -> LDS) and c0 (fp32 registers), broadcast over batch
    float c_reg[4];
    {
        uint16_t h0[4];
#pragma unroll
        for (int r = 0; r < 4; ++r) {
            h0[r]    = f2bf(init_state[j0 + r]);
            c_reg[r] = init_state[128 + j0 + r];
        }
        *(short4v*)&hx[0][l15][j0] = *(short4v*)h0;
    }
    __syncthreads();   // ids_l + h0 visible

    // stage x[:,0] into buffer 0
    {
        int id = ids_l[row * kL];
        const float* erow = embed + (size_t)id * kInit + c16 * 8;
        if (c16 < 16) *(short8*)&hx[0][row][128 + c16 * 8] = cvt8(erow);
        else {
            ((float4*)&xcf[0][row][(c16 - 16) * 8])[0] = ((const float4*)erow)[0];
            ((float4*)&xcf[0][row][(c16 - 16) * 8])[1] = ((const float4*)erow)[1];
        }
    }
    __syncthreads();

    const float K1 = 1.442695041f;   // log2(e)
    const float K2 = 2.885390082f;   // 2*log2(e)

    for (int t = 0; t < kL; ++t) {
        const int cur = t & 1, nxt = cur ^ 1;

        // prefetch x[:, t+1] (global load latency hidden under K-loop)
        const int tn = (t + 1 < kL) ? t + 1 : kL - 1;
        int id = ids_l[row * kL + tn];
        const float* erow = embed + (size_t)id * kInit + c16 * 8;
        float4 xa = ((const float4*)erow)[0];
        float4 xb = ((const float4*)erow)[1];

        // K-loop: z^T 16x16 tiles, acc init = bias
        floatx4 acc[5];
#pragma unroll
        for (int g = 0; g < 5; ++g) acc[g] = bias4[g];
        const uint16_t* hxr = &hx[cur][l15][0];
#pragma unroll
        for (int kk = 0; kk < 8; ++kk) {
            short8 xf = *(const short8*)(hxr + kk * 32 + quad * 8);  // B frag
#pragma unroll
            for (int g = 0; g < 5; ++g)
                acc[g] = __builtin_amdgcn_mfma_f32_16x16x32_bf16(wf[g][kk], xf, acc[g], 0, 0, 0);
        }

        // staged x -> next buffers (disjoint from hx[cur] reads & h writes)
        if (c16 < 16) {
            uint16_t xv[8];
            xv[0]=f2bf(xa.x); xv[1]=f2bf(xa.y); xv[2]=f2bf(xa.z); xv[3]=f2bf(xa.w);
            xv[4]=f2bf(xb.x); xv[5]=f2bf(xb.y); xv[6]=f2bf(xb.z); xv[7]=f2bf(xb.w);
            *(short8*)&hx[nxt][row][128 + c16 * 8] = *(short8*)xv;
        } else {
            ((float4*)&xcf[nxt][row][(c16 - 16) * 8])[0] = xa;
            ((float4*)&xcf[nxt][row][(c16 - 16) * 8])[1] = xb;
        }

        // gates: lane owns (b=l15, j=j0..j0+3); all 5 gates in acc[g][r]
        float rcv[4];
#pragma unroll
        for (int r = 0; r < 4; ++r) rcv[r] = xcf[cur][l15][j0 + r];
        uint16_t hv[4];
        float hf[4];
#pragma unroll
        for (int r = 0; r < 4; ++r) {
            float a  = clampf(acc[0][r], -15.f, 15.f);
            float ii = clampf(acc[1][r], -30.f, 30.f);
            float f1 = clampf(acc[2][r], -30.f, 30.f);
            float f2 = clampf(acc[3][r], -30.f, 30.f);
            float oo = clampf(acc[4][r], -30.f, 30.f);

            // tanh(a)*sigmoid(i), one rcp
            float Ea = exp2f(a * K2);                 // e^{2a}  <= 2^43.3
            float Ei = exp2f(-ii * K1);               // e^{-i}  <= 2^43.3
            float P  = (Ea - 1.0f) * __builtin_amdgcn_rcpf((Ea + 1.0f) * (1.0f + Ei));
            // sigmoid(f1)*lc + sigmoid(f2)*rc, one rcp
            float E1 = exp2f(f1 * K1), E2 = exp2f(f2 * K1);   // <= 2^43.3
            float lc = c_reg[r], rc = rcv[r];
            float num = E1 * (1.0f + E2) * lc + E2 * (1.0f + E1) * rc;
            float Q  = num * __builtin_amdgcn_rcpf((1.0f + E1) * (1.0f + E2));
            float c  = P + Q;
            c_reg[r] = c;
            // sigmoid(o)*tanh(c), one rcp
            float Eo = exp2f(-oo * K1);
            float cc = clampf(c, -15.f, 15.f);
            float Ec = exp2f(cc * K2);
            float h  = (Ec - 1.0f) * __builtin_amdgcn_rcpf((1.0f + Eo) * (Ec + 1.0f));
            hv[r] = f2bf(h);
            hf[r] = h;
        }
        *(short4v*)&hx[nxt][l15][j0] = *(short4v*)hv;
        if (t == kL - 1) {
#pragma unroll
            for (int r = 0; r < 4; ++r) hfin[l15][j0 + r] = hf[r];
        }
        __syncthreads();
    }

    // final: out[b][o] = sum_j hfin[b][j]*final_w[o][j] + final_b[o]
    if (tid < 192) {
        int b = tid / 12, rem = tid % 12;
        int o = rem >> 2, q4 = rem & 3;
        float s = 0.f;
        const float* wrow = final_w + o * kState;
#pragma unroll 8
        for (int j = q4 * 32; j < q4 * 32 + 32; ++j)
            s += hfin[b][j] * wrow[j];
        partial[b][o][q4] = s;
    }
    __syncthreads();
    if (tid < 48) {
        int b = tid / 3, o = tid % 3;
        float s = partial[b][o][0] + partial[b][o][1] +
                  partial[b][o][2] + partial[b][o][3] + final_b[o];
        out[(b0 + b) * 3 + o] = s;
    }
}

extern "C" void kernel_launch(void* const* d_in, const int* in_sizes, int n_in,
                              void* d_out, int out_size, void* d_ws, size_t ws_size,
                              hipStream_t stream) {
    const int*   ids        = (const int*)d_in[0];
    const float* embed      = (const float*)d_in[1];
    const float* whx_w      = (const float*)d_in[2];
    const float* whx_b      = (const float*)d_in[3];
    const float* init_state = (const float*)d_in[4];
    const float* final_w    = (const float*)d_in[5];
    const float* final_b    = (const float*)d_in[6];
    float*       out        = (float*)d_out;
    hipLaunchKernelGGL(tree_lstm_kernel, dim3(kBlocks), dim3(kThreads), 0, stream,
                       ids, embed, whx_w, whx_b, init_state, final_w, final_b, out);
}

// Round 3
// 399.796 us; speedup vs baseline: 1.0116x; 1.0116x over previous
//
#include <hip/hip_runtime.h>
#include <stdint.h>

// Tree-LSTM scan: B=256, L=128, STATE=128, INIT=256, Z=5*128=640. fp32 I/O.
// 16 blocks x 512 threads; block owns 16 batch rows; bf16 weights register-
// resident (160 VGPR/lane, pinned via amdgpu_waves_per_eu(2,2) => 256-VGPR
// budget, 2 waves/EU, 1 block/CU); recurrence block-local (no grid sync).

constexpr int kL      = 128;
constexpr int kState  = 128;
constexpr int kInit   = 256;
constexpr int kRows   = 16;
constexpr int kBlocks = 16;
constexpr int kThreads= 512;
constexpr int kHxStr  = 264;   // bf16 elems: [h 0:128 | x_rh 128:256 | pad 8]
constexpr int kXcStr  = 132;   // fp32 elems: right_c 128 + pad 4

typedef __attribute__((ext_vector_type(8))) short short8;    // MFMA A/B frag
typedef __attribute__((ext_vector_type(4))) short short4v;
typedef __attribute__((ext_vector_type(4))) float floatx4;   // MFMA C/D frag

__device__ __forceinline__ uint16_t f2bf(float f) {
    union { float f; uint32_t i; } v; v.f = f;
    return (uint16_t)((v.i + 0x7FFFu + ((v.i >> 16) & 1u)) >> 16);  // RNE
}
__device__ __forceinline__ short8 cvt8(const float* p) {
    float4 a = ((const float4*)p)[0];
    float4 b = ((const float4*)p)[1];
    short8 r;
    r[0]=f2bf(a.x); r[1]=f2bf(a.y); r[2]=f2bf(a.z); r[3]=f2bf(a.w);
    r[4]=f2bf(b.x); r[5]=f2bf(b.y); r[6]=f2bf(b.z); r[7]=f2bf(b.w);
    return r;
}
__device__ __forceinline__ float clampf(float x, float lo, float hi) {
    return fminf(fmaxf(x, lo), hi);
}

__global__ __launch_bounds__(kThreads)
__attribute__((amdgpu_waves_per_eu(2, 2)))
void tree_lstm_kernel(const int* __restrict__ ids,
                      const float* __restrict__ embed,
                      const float* __restrict__ whx_w,
                      const float* __restrict__ whx_b,
                      const float* __restrict__ init_state,
                      const float* __restrict__ final_w,
                      const float* __restrict__ final_b,
                      float* __restrict__ out)
{
    __shared__ alignas(16) uint16_t hx[2][kRows][kHxStr];  // bf16 [h | right_h]
    __shared__ alignas(16) float    xcf[2][kRows][kXcStr]; // fp32 right_c
    __shared__ int   ids_l[kRows * kL];
    __shared__ alignas(16) float bias_l[5 * kState];       // fp32 bias
    __shared__ float hfin[kRows][kState + 4];              // fp32 final h
    __shared__ float partial[kRows][3][4];

    const int tid  = threadIdx.x;
    const int w    = tid >> 6;        // wave 0..7 -> j-slice [16w,16w+16)
    const int lane = tid & 63;
    const int l15  = lane & 15;       // batch row (MFMA D col / B col)
    const int quad = lane >> 4;       // 0..3
    const int b0   = blockIdx.x * kRows;
    const int j0   = w * 16 + quad * 4;   // 4 consecutive j (MFMA D rows)
    const int row  = tid >> 5;        // staging: batch row 0..15
    const int c16  = tid & 31;        // staging: 8-elem chunk of 256-elem x row

    // ids -> LDS, coalesced
    ((int4*)ids_l)[tid] = ((const int4*)(ids + b0 * kL))[tid];
    // bias -> LDS (NOT registers: saves 20 VGPRs; __syncthreads in the t-loop
    // is an LDS barrier so per-step reads below cannot be hoisted back)
    if (tid < 5 * kState) bias_l[tid] = whx_b[tid];

    // register-resident A-frags of z^T = W * hx^T (fp32 -> bf16 RNE)
    // A layout: m = lane&15 (W row n0+l15), k = kk*32 + quad*8 + [0..8)
    short8 wf[5][8];
#pragma unroll
    for (int g = 0; g < 5; ++g) {
        const float* wrow = whx_w + (size_t)(g * 128 + w * 16 + l15) * kInit;
#pragma unroll
        for (int kk = 0; kk < 8; ++kk)
            wf[g][kk] = cvt8(wrow + kk * 32 + quad * 8);
    }

    // init h0 (bf16 -> LDS) and c0 (fp32 registers), broadcast over batch
    float c_reg[4];
    {
        uint16_t h0[4];
#pragma unroll
        for (int r = 0; r < 4; ++r) {
            h0[r]    = f2bf(init_state[j0 + r]);
            c_reg[r] = init_state[128 + j0 + r];
        }
        *(short4v*)&hx[0][l15][j0] = *(short4v*)h0;
    }
    __syncthreads();   // ids_l + bias + h0 visible

    // stage x[:,0] into buffer 0
    {
        int id = ids_l[row * kL];
        const float* erow = embed + (size_t)id * kInit + c16 * 8;
        if (c16 < 16) *(short8*)&hx[0][row][128 + c16 * 8] = cvt8(erow);
        else {
            ((float4*)&xcf[0][row][(c16 - 16) * 8])[0] = ((const float4*)erow)[0];
            ((float4*)&xcf[0][row][(c16 - 16) * 8])[1] = ((const float4*)erow)[1];
        }
    }
    __syncthreads();

    const float K1 = 1.442695041f;   // log2(e)
    const float K2 = 2.885390082f;   // 2*log2(e)

    for (int t = 0; t < kL; ++t) {
        const int cur = t & 1, nxt = cur ^ 1;

        // prefetch x[:, t+1] (global load latency hidden under K-loop)
        const int tn = (t + 1 < kL) ? t + 1 : kL - 1;
        int id = ids_l[row * kL + tn];
        const float* erow = embed + (size_t)id * kInit + c16 * 8;
        float4 xa = ((const float4*)erow)[0];
        float4 xb = ((const float4*)erow)[1];

        // acc init = bias (b128 broadcast reads: 16 lanes/quad same address)
        floatx4 acc[5];
#pragma unroll
        for (int g = 0; g < 5; ++g)
            acc[g] = *(const floatx4*)&bias_l[g * 128 + j0];

        // K-loop: z^T 16x16 tiles
        const uint16_t* hxr = &hx[cur][l15][0];
#pragma unroll
        for (int kk = 0; kk < 8; ++kk) {
            short8 xf = *(const short8*)(hxr + kk * 32 + quad * 8);  // B frag
#pragma unroll
            for (int g = 0; g < 5; ++g)
                acc[g] = __builtin_amdgcn_mfma_f32_16x16x32_bf16(wf[g][kk], xf, acc[g], 0, 0, 0);
        }

        // staged x -> next buffers (disjoint from hx[cur] reads & h writes)
        if (c16 < 16) {
            uint16_t xv[8];
            xv[0]=f2bf(xa.x); xv[1]=f2bf(xa.y); xv[2]=f2bf(xa.z); xv[3]=f2bf(xa.w);
            xv[4]=f2bf(xb.x); xv[5]=f2bf(xb.y); xv[6]=f2bf(xb.z); xv[7]=f2bf(xb.w);
            *(short8*)&hx[nxt][row][128 + c16 * 8] = *(short8*)xv;
        } else {
            ((float4*)&xcf[nxt][row][(c16 - 16) * 8])[0] = xa;
            ((float4*)&xcf[nxt][row][(c16 - 16) * 8])[1] = xb;
        }

        // gates: lane owns (b=l15, j=j0..j0+3); all 5 gates in acc[g][r]
        floatx4 rcv = *(const floatx4*)&xcf[cur][l15][j0];
        uint16_t hv[4];
        float hf[4];
#pragma unroll
        for (int r = 0; r < 4; ++r) {
            float a  = clampf(acc[0][r], -15.f, 15.f);
            float ii = clampf(acc[1][r], -30.f, 30.f);
            float f1 = clampf(acc[2][r], -30.f, 30.f);
            float f2 = clampf(acc[3][r], -30.f, 30.f);
            float oo = clampf(acc[4][r], -30.f, 30.f);

            // tanh(a)*sigmoid(i), one rcp
            float Ea = exp2f(a * K2);                 // e^{2a}  <= 2^43.3
            float Ei = exp2f(-ii * K1);               // e^{-i}  <= 2^43.3
            float P  = (Ea - 1.0f) * __builtin_amdgcn_rcpf((Ea + 1.0f) * (1.0f + Ei));
            // sigmoid(f1)*lc + sigmoid(f2)*rc, one rcp
            float E1 = exp2f(f1 * K1), E2 = exp2f(f2 * K1);   // <= 2^43.3
            float lc = c_reg[r], rc = rcv[r];
            float num = E1 * (1.0f + E2) * lc + E2 * (1.0f + E1) * rc;
            float Q  = num * __builtin_amdgcn_rcpf((1.0f + E1) * (1.0f + E2));
            float c  = P + Q;
            c_reg[r] = c;
            // sigmoid(o)*tanh(c), one rcp
            float Eo = exp2f(-oo * K1);
            float cc = clampf(c, -15.f, 15.f);
            float Ec = exp2f(cc * K2);
            float h  = (Ec - 1.0f) * __builtin_amdgcn_rcpf((1.0f + Eo) * (Ec + 1.0f));
            hv[r] = f2bf(h);
            hf[r] = h;
        }
        *(short4v*)&hx[nxt][l15][j0] = *(short4v*)hv;
        if (t == kL - 1) {
#pragma unroll
            for (int r = 0; r < 4; ++r) hfin[l15][j0 + r] = hf[r];
        }
        __syncthreads();
    }

    // final: out[b][o] = sum_j hfin[b][j]*final_w[o][j] + final_b[o]
    if (tid < 192) {
        int b = tid / 12, rem = tid % 12;
        int o = rem >> 2, q4 = rem & 3;
        float s = 0.f;
        const float* wrow = final_w + o * kState;
#pragma unroll 8
        for (int j = q4 * 32; j < q4 * 32 + 32; ++j)
            s += hfin[b][j] * wrow[j];
        partial[b][o][q4] = s;
    }
    __syncthreads();
    if (tid < 48) {
        int b = tid / 3, o = tid % 3;
        float s = partial[b][o][0] + partial[b][o][1] +
                  partial[b][o][2] + partial[b][o][3] + final_b[o];
        out[(b0 + b) * 3 + o] = s;
    }
}

extern "C" void kernel_launch(void* const* d_in, const int* in_sizes, int n_in,
                              void* d_out, int out_size, void* d_ws, size_t ws_size,
                              hipStream_t stream) {
    const int*   ids        = (const int*)d_in[0];
    const float* embed      = (const float*)d_in[1];
    const float* whx_w      = (const float*)d_in[2];
    const float* whx_b      = (const float*)d_in[3];
    const float* init_state = (const float*)d_in[4];
    const float* final_w    = (const float*)d_in[5];
    const float* final_b    = (const float*)d_in[6];
    float*       out        = (float*)d_out;
    hipLaunchKernelGGL(tree_lstm_kernel, dim3(kBlocks), dim3(kThreads), 0, stream,
                       ids, embed, whx_w, whx_b, init_state, final_w, final_b, out);
}